// Round 2
// baseline (910.563 us; speedup 1.0000x reference)
//
#include <hip/hip_runtime.h>

#define DD 32768
#define NN 512
#define PP 8
#define NACC 44    // 36 packed xtx + 8 xty

__device__ __forceinline__ float softplus_f(float x) {
    // stable: max(x,0) + log1p(exp(-|x|))  (matches jax.nn.softplus)
    return fmaxf(x, 0.0f) + log1pf(__expf(-fabsf(x)));
}

__device__ __forceinline__ float transform_y(float yv, float is, float hw, float hb) {
    float yc = fminf(fmaxf(yv, 1e-35f), 1.0f);
    float ym = fminf(fmaxf(1.0f - yv, 1e-35f), 1.0f);
    float t  = (__logf(yc) - __logf(ym)) * 10.0f * is;
    return fmaf(softplus_f(t), hw, t) + hb;
}

// One wave per d; each lane owns 2 consecutive rows per iteration so the
// row-pair (80 B) is 16-B aligned -> 5 dense float4 loads per lane.
// Butterfly-reduce 44 sums; lanes 0..43 store sum[lane] to transposed
// scratch ws[k*DD + d] (coalesced for the consumer).
__global__ __launch_bounds__(256) void k_sums(
    const float* __restrict__ y,
    const float* __restrict__ design,
    const float* __restrict__ inv_scale,
    const float* __restrict__ h1w,
    const float* __restrict__ h1b,
    float* __restrict__ ws)
{
    const int lane = threadIdx.x & 63;
    const int d    = blockIdx.x * 4 + (threadIdx.x >> 6);

    float acc[NACC];
#pragma unroll
    for (int k = 0; k < NACC; ++k) acc[k] = 0.0f;

    const float4* dp4 = (const float4*)(design + (size_t)d * (NN * 10));
    const float2* yp2 = (const float2*)(y + (size_t)d * NN);
    const float2* is2 = (const float2*)inv_scale;
    const float2* hw2 = (const float2*)h1w;
    const float2* hb2 = (const float2*)h1b;

#pragma unroll 1
    for (int i = 0; i < NN / 128; ++i) {      // 4 iterations, 2 rows/lane each
        const int m = i * 64 + lane;          // row-pair index
        float4 b0 = dp4[m * 5 + 0];           // row0 cols 0..3
        float4 b1 = dp4[m * 5 + 1];           // row0 cols 4..7
        float4 b2 = dp4[m * 5 + 2];           // row0 cols 8,9 | row1 cols 0,1
        float4 b3 = dp4[m * 5 + 3];           // row1 cols 2..5
        float4 b4 = dp4[m * 5 + 4];           // row1 cols 6..9
        float2 yv = yp2[m];
        float2 is = is2[m];
        float2 hw = hw2[m];
        float2 hb = hb2[m];

        const float X0[8] = {b0.x, b0.y, b0.z, b0.w, b1.x, b1.y, b1.z, b1.w};
        const float X1[8] = {b2.z, b2.w, b3.x, b3.y, b3.z, b3.w, b4.x, b4.y};

        float yt0 = transform_y(yv.x, is.x, hw.x, hb.x);
        float yt1 = transform_y(yv.y, is.y, hw.y, hb.y);

        int k = 0;
#pragma unroll
        for (int p = 0; p < PP; ++p) {
#pragma unroll
            for (int q = 0; q <= p; ++q, ++k) {
                acc[k] = fmaf(X0[p], X0[q], acc[k]);
                acc[k] = fmaf(X1[p], X1[q], acc[k]);
            }
        }
#pragma unroll
        for (int p = 0; p < PP; ++p) {
            acc[36 + p] = fmaf(X0[p], yt0, acc[36 + p]);
            acc[36 + p] = fmaf(X1[p], yt1, acc[36 + p]);
        }
    }

#pragma unroll
    for (int off = 32; off; off >>= 1) {
#pragma unroll
        for (int k = 0; k < NACC; ++k) acc[k] += __shfl_xor(acc[k], off, 64);
    }

    // lane k stores sum k (all lanes hold identical reduced values)
    float myv = 0.0f;
#pragma unroll
    for (int k = 0; k < NACC; ++k) myv = (lane == k) ? acc[k] : myv;
    if (lane < NACC) ws[(size_t)lane * DD + d] = myv;
}

// One thread per d: coalesced reads of transposed sums, 8x8 Cholesky solve,
// coalesced mu write.
__global__ __launch_bounds__(256) void k_solve(
    const float* __restrict__ ws,
    const float* __restrict__ regu,
    float* __restrict__ mu_out)
{
    const int d = blockIdx.x * blockDim.x + threadIdx.x;

    float s[NACC];
#pragma unroll
    for (int k = 0; k < NACC; ++k) s[k] = ws[(size_t)k * DD + d];

    float A[PP][PP];   // lower triangle used
    {
        int k = 0;
#pragma unroll
        for (int p = 0; p < PP; ++p)
#pragma unroll
            for (int q = 0; q <= p; ++q, ++k) A[p][q] = s[k];
    }
    float b[PP];
#pragma unroll
    for (int p = 0; p < PP; ++p) b[p] = s[36 + p];
#pragma unroll
    for (int p = 0; p < PP; ++p) A[p][p] += softplus_f(regu[(size_t)d * PP + p]);

    // Cholesky factorization in the lower triangle of A
    float dinv[PP];
#pragma unroll
    for (int j = 0; j < PP; ++j) {
        float v = A[j][j];
#pragma unroll
        for (int k = 0; k < j; ++k) v -= A[j][k] * A[j][k];
        float lj = sqrtf(v);
        float iv = 1.0f / lj;
        A[j][j] = lj;
        dinv[j] = iv;
#pragma unroll
        for (int i = j + 1; i < PP; ++i) {
            float u = A[i][j];
#pragma unroll
            for (int k = 0; k < j; ++k) u -= A[i][k] * A[j][k];
            A[i][j] = u * iv;
        }
    }
    float z[PP];
#pragma unroll
    for (int i = 0; i < PP; ++i) {
        float v = b[i];
#pragma unroll
        for (int k = 0; k < i; ++k) v -= A[i][k] * z[k];
        z[i] = v * dinv[i];
    }
    float m[PP];
#pragma unroll
    for (int i = PP - 1; i >= 0; --i) {
        float v = z[i];
#pragma unroll
        for (int k = i + 1; k < PP; ++k) v -= A[k][i] * m[k];
        m[i] = v * dinv[i];
    }

    float4* om = (float4*)(mu_out + (size_t)d * PP);
    om[0] = make_float4(m[0], m[1], m[2], m[3]);
    om[1] = make_float4(m[4], m[5], m[6], m[7]);
}

// Elementwise coalesced scatter of packed-tril scale_tril into (D,8,8) L.
__global__ __launch_bounds__(256) void k_L(
    const float* __restrict__ scale_tril,
    float* __restrict__ Lout)
{
    const int idx = blockIdx.x * blockDim.x + threadIdx.x;   // DD*64 total
    const int d  = idx >> 6;
    const int rc = idx & 63;
    const int r  = rc >> 3;
    const int c  = rc & 7;
    float v = 0.0f;
    if (c <= r) v = scale_tril[(size_t)d * 36 + ((r * (r + 1)) >> 1) + c];
    Lout[idx] = v;
}

extern "C" void kernel_launch(void* const* d_in, const int* in_sizes, int n_in,
                              void* d_out, int out_size, void* d_ws, size_t ws_size,
                              hipStream_t stream) {
    const float* y          = (const float*)d_in[0];
    const float* design     = (const float*)d_in[1];
    const float* inv_scale  = (const float*)d_in[2];
    const float* h1w        = (const float*)d_in[3];
    const float* h1b        = (const float*)d_in[4];
    const float* scale_tril = (const float*)d_in[5];
    const float* regu       = (const float*)d_in[6];
    // d_in[7] = target_label (always 0 -> p = 8), unused

    float* out = (float*)d_out;
    float* ws  = (float*)d_ws;                 // 44*DD*4 = 5.8 MB needed

    hipLaunchKernelGGL(k_sums, dim3(DD / 4), dim3(256), 0, stream,
                       y, design, inv_scale, h1w, h1b, ws);
    hipLaunchKernelGGL(k_solve, dim3(DD / 256), dim3(256), 0, stream,
                       ws, regu, out);
    hipLaunchKernelGGL(k_L, dim3(DD * 64 / 256), dim3(256), 0, stream,
                       scale_tril, out + (size_t)DD * 8);
}